// Round 1
// baseline (545.432 us; speedup 1.0000x reference)
//
#include <hip/hip_runtime.h>

// detection_head: six 1x1 convs over [4,252,252,384] fp32 -> 52 channels.
// Strategy: per-pixel GEMM M=254016, K=384, N=52 (padded to 64) via
// mfma_f32_16x16x32_bf16. Memory-bound (~443 MB/launch); bf16 MFMA makes
// compute negligible vs the fp32-VALU alternative.

#define HH 252
#define WW 252
#define BB 4
#define CIN 384
#define PIX (BB*HH*WW)            // 254016
#define NPAD 64
#define KPAD 392                  // 384 + 8 bf16 pad -> row stride 784 B (bank offset 4)
#define WIMG_USHORTS (NPAD*KPAD)  // 25088
#define WIMG_BYTES (WIMG_USHORTS*2)       // 50176
#define LDS_BYTES (WIMG_BYTES + NPAD*4)   // 50432

typedef __attribute__((ext_vector_type(8))) short short8;
typedef __attribute__((ext_vector_type(4))) float f32x4;
typedef __attribute__((ext_vector_type(4))) unsigned int uint4v;

__device__ __forceinline__ unsigned bfpk(float a, float b) {
  // two RNE bf16 packed into one u32 (low = a, high = b)
  unsigned ua = __float_as_uint(a), ub = __float_as_uint(b);
  ua = (ua + 0x7FFFu + ((ua >> 16) & 1u)) >> 16;
  ub = (ub + 0x7FFFu + ((ub >> 16) & 1u)) >> 16;
  return ua | (ub << 16);
}
__device__ __forceinline__ unsigned short f2bf(float a) {
  unsigned ua = __float_as_uint(a);
  return (unsigned short)((ua + 0x7FFFu + ((ua >> 16) & 1u)) >> 16);
}

// Pack the 6 weight matrices into bf16 image [64][KPAD] (rows 52..63 and
// cols 384..391 zero) + 64 fp32 biases. Runs every launch (ws is re-poisoned).
__global__ void prep_kernel(
    const float* __restrict__ occ_w, const float* __restrict__ occ_b,
    const float* __restrict__ loc_w, const float* __restrict__ loc_b,
    const float* __restrict__ ang_w, const float* __restrict__ ang_b,
    const float* __restrict__ siz_w, const float* __restrict__ siz_b,
    const float* __restrict__ hea_w, const float* __restrict__ hea_b,
    const float* __restrict__ clf_w, const float* __restrict__ clf_b,
    unsigned short* __restrict__ wimg, float* __restrict__ bimg) {
  int idx = blockIdx.x * 256 + threadIdx.x;
  if (idx < WIMG_USHORTS) {
    int n = idx / KPAD, k = idx % KPAD;
    float v = 0.f;
    if (k < CIN) {
      const float* w = nullptr; int lo = 0;
      if      (n < 4)  { w = occ_w; lo = n; }
      else if (n < 16) { w = loc_w; lo = n - 4; }
      else if (n < 20) { w = ang_w; lo = n - 16; }
      else if (n < 32) { w = siz_w; lo = n - 20; }
      else if (n < 36) { w = hea_w; lo = n - 32; }
      else if (n < 52) { w = clf_w; lo = n - 36; }
      if (w) v = w[lo * CIN + k];
    }
    wimg[idx] = f2bf(v);
  } else if (idx < WIMG_USHORTS + NPAD) {
    int c = idx - WIMG_USHORTS;
    float v = 0.f;
    if      (c < 4)  v = occ_b[c];
    else if (c < 16) v = loc_b[c - 4];
    else if (c < 20) v = ang_b[c - 16];
    else if (c < 32) v = siz_b[c - 20];
    else if (c < 36) v = hea_b[c - 32];
    else if (c < 52) v = clf_b[c - 36];
    bimg[c] = v;
  }
}

// Block = 256 threads = 4 waves; 64 pixels/block (wave handles M=16 x N=64).
// Weights staged to LDS once; K-loop has no barriers.
__global__ __launch_bounds__(256, 3) void head_kernel(
    const float* __restrict__ x, const uint4v* __restrict__ wsimg,
    float* __restrict__ out) {
  __shared__ __align__(16) unsigned char lds_raw[LDS_BYTES];
  {
    uint4v* dst = (uint4v*)lds_raw;
    for (int u = threadIdx.x; u < LDS_BYTES / 16; u += 256) dst[u] = wsimg[u];
  }
  __syncthreads();
  const unsigned short* Wl = (const unsigned short*)lds_raw;
  const float* biasl = (const float*)(lds_raw + WIMG_BYTES);

  const int lane = threadIdx.x & 63;
  const int wave = threadIdx.x >> 6;
  const int m = lane & 15;        // A row / B col / C col
  const int quad = lane >> 4;     // k-group for A/B; row-group for C
  const int pixel_base = blockIdx.x * 64 + wave * 16;
  const float* xrow = x + (size_t)(pixel_base + m) * CIN + quad * 8;

  f32x4 acc0 = {0.f, 0.f, 0.f, 0.f};
  f32x4 acc1 = {0.f, 0.f, 0.f, 0.f};
  f32x4 acc2 = {0.f, 0.f, 0.f, 0.f};
  f32x4 acc3 = {0.f, 0.f, 0.f, 0.f};

  const unsigned short* wbase = Wl + (size_t)m * KPAD + quad * 8;

  #pragma unroll 4
  for (int kit = 0; kit < 12; ++kit) {
    const f32x4* px = (const f32x4*)(xrow + kit * 32);
    f32x4 f0 = px[0];
    f32x4 f1 = px[1];
    union { unsigned u[4]; short8 s; } a;
    a.u[0] = bfpk(f0.x, f0.y);
    a.u[1] = bfpk(f0.z, f0.w);
    a.u[2] = bfpk(f1.x, f1.y);
    a.u[3] = bfpk(f1.z, f1.w);
    const unsigned short* wk = wbase + kit * 32;
    short8 b0 = *(const short8*)(wk);
    short8 b1 = *(const short8*)(wk + 16 * KPAD);
    short8 b2 = *(const short8*)(wk + 32 * KPAD);
    short8 b3 = *(const short8*)(wk + 48 * KPAD);
    acc0 = __builtin_amdgcn_mfma_f32_16x16x32_bf16(a.s, b0, acc0, 0, 0, 0);
    acc1 = __builtin_amdgcn_mfma_f32_16x16x32_bf16(a.s, b1, acc1, 0, 0, 0);
    acc2 = __builtin_amdgcn_mfma_f32_16x16x32_bf16(a.s, b2, acc2, 0, 0, 0);
    acc3 = __builtin_amdgcn_mfma_f32_16x16x32_bf16(a.s, b3, acc3, 0, 0, 0);
  }

  // Epilogue: C/D layout col = lane&15 (channel within n-tile),
  // row = quad*4 + reg (pixel within m-tile). Map channel c -> tensor.
  f32x4 accs[4] = {acc0, acc1, acc2, acc3};
  #pragma unroll
  for (int nt = 0; nt < 4; ++nt) {
    int c = nt * 16 + m;
    if (c < 52) {
      size_t base; int stride, ch; bool sig = false;
      if      (c < 4)  { base = 0;                stride = 4;  ch = c;      sig = true; }
      else if (c < 16) { base = (size_t)PIX * 4;  stride = 12; ch = c - 4;  }
      else if (c < 20) { base = (size_t)PIX * 16; stride = 4;  ch = c - 16; }
      else if (c < 32) { base = (size_t)PIX * 20; stride = 12; ch = c - 20; }
      else if (c < 36) { base = (size_t)PIX * 32; stride = 4;  ch = c - 32; sig = true; }
      else             { base = (size_t)PIX * 36; stride = 16; ch = c - 36; }
      float bv = biasl[c];
      #pragma unroll
      for (int r = 0; r < 4; ++r) {
        int p = pixel_base + quad * 4 + r;
        float v = accs[nt][r] + bv;
        if (sig) v = 1.f / (1.f + __expf(-v));
        out[base + (size_t)p * stride + ch] = v;
      }
    }
  }
}

extern "C" void kernel_launch(void* const* d_in, const int* in_sizes, int n_in,
                              void* d_out, int out_size, void* d_ws, size_t ws_size,
                              hipStream_t stream) {
  const float* x     = (const float*)d_in[0];
  const float* occ_w = (const float*)d_in[1];
  const float* occ_b = (const float*)d_in[2];
  const float* loc_w = (const float*)d_in[3];
  const float* loc_b = (const float*)d_in[4];
  const float* ang_w = (const float*)d_in[5];
  const float* ang_b = (const float*)d_in[6];
  const float* siz_w = (const float*)d_in[7];
  const float* siz_b = (const float*)d_in[8];
  const float* hea_w = (const float*)d_in[9];
  const float* hea_b = (const float*)d_in[10];
  const float* clf_w = (const float*)d_in[11];
  const float* clf_b = (const float*)d_in[12];

  unsigned short* wimg = (unsigned short*)d_ws;
  float* bimg = (float*)((char*)d_ws + WIMG_BYTES);

  prep_kernel<<<(WIMG_USHORTS + NPAD + 255) / 256, 256, 0, stream>>>(
      occ_w, occ_b, loc_w, loc_b, ang_w, ang_b, siz_w, siz_b, hea_w, hea_b,
      clf_w, clf_b, wimg, bimg);

  head_kernel<<<PIX / 64, 256, 0, stream>>>(x, (const uint4v*)d_ws,
                                            (float*)d_out);
}